// Round 17
// baseline (287.507 us; speedup 1.0000x reference)
//
#include <hip/hip_runtime.h>
#include <cstdint>

#define BB 8
#define LL 4096
#define DD 1024
#define HH 16
#define KSEL 409
#define NT3 3072
#define MTOT (BB * KSEL)   // 3272 flat selected rows
#define PK 40              // padded LDS pitch (u16) for reg-staged A tiles
#define VP 448             // vT key-pitch

typedef unsigned short u16;
typedef unsigned int u32;
typedef __attribute__((ext_vector_type(4))) unsigned int ux4;
typedef __attribute__((ext_vector_type(4))) unsigned short us4;
typedef __attribute__((ext_vector_type(8))) short short8;
typedef __attribute__((ext_vector_type(4))) float f32x4;

typedef const u32 __attribute__((address_space(1)))* gas_p;
typedef u32 __attribute__((address_space(3)))* las_p;

__device__ __forceinline__ void dma16(const void* g, void* l) {
  __builtin_amdgcn_global_load_lds((gas_p)g, (las_p)l, 16, 0, 0);
}

__device__ __forceinline__ u16 bfh(float f) {
  unsigned u = __float_as_uint(f);
  return (u16)((u + 0x7fffu + ((u >> 16) & 1u)) >> 16);
}
__device__ __forceinline__ float bff(u16 h) { return __uint_as_float(((unsigned)h) << 16); }

__device__ __forceinline__ void cvt8(const float* v, ux4& H, ux4& L) {
#pragma unroll
  for (int i = 0; i < 4; i++) {
    u16 h0 = bfh(v[2 * i]), h1 = bfh(v[2 * i + 1]);
    u16 l0 = bfh(v[2 * i] - bff(h0));
    u16 l1 = bfh(v[2 * i + 1] - bff(h1));
    H[i] = (unsigned)h0 | ((unsigned)h1 << 16);
    L[i] = (unsigned)l0 | ((unsigned)l1 << 16);
  }
}

#define MFMA16(A, B, C) __builtin_amdgcn_mfma_f32_16x16x32_bf16(A, B, C, 0, 0, 0)

// ---------- prep: fp32 weight [K][N] -> split-bf16 K-packed [s][n][32] ----------
__global__ __launch_bounds__(256) void k_prep(const float* __restrict__ w, int N,
                                              u16* __restrict__ h, u16* __restrict__ l) {
  __shared__ float T[32][257];
  const int t = threadIdx.x;
  const int n0 = blockIdx.x * 256, s = blockIdx.y;
#pragma unroll 4
  for (int r = 0; r < 32; r++) T[r][t] = w[((long)(s * 32 + r)) * N + n0 + t];
  __syncthreads();
  const long base = ((long)s * N + n0 + t) * 32;
#pragma unroll
  for (int q = 0; q < 4; q++) {
    float v[8];
#pragma unroll
    for (int i = 0; i < 8; i++) v[i] = T[q * 8 + i][t];
    ux4 H, L;
    cvt8(v, H, L);
    *(ux4*)(h + base + q * 8) = H;
    if (l) *(ux4*)(l + base + q * 8) = L;
  }
}

// ---------- scorer (R14 proven): counted-vmcnt pipeline; B dbuf DMA; 3-term ----
// vmcnt(12): 2 y-stores + 2 x-prefetch + 8 next-tile DMAs stay in flight
__global__ __launch_bounds__(256) void k_score(
    const float* __restrict__ x, const u16* __restrict__ w1h, const u16* __restrict__ w1l,
    const float* __restrict__ b1, const float* __restrict__ w2,
    float* __restrict__ z, float* __restrict__ y) {
  __shared__ u16 Ah[64 * PK], Al[64 * PK];        // 10.2 KB (single buf)
  __shared__ u16 Bh[2][256 * 32], Bl[2][256 * 32];// 64 KB (double buf, DMA)
  __shared__ float zp[64][4];
  const int t = threadIdx.x;
  const long t0 = (long)blockIdx.x * 64;
  const int w = t >> 6, lane = t & 63;
  const int g = lane >> 4, qi = lane & 15;
  f32x4 acc[4][4];
#pragma unroll
  for (int i = 0; i < 4; i++)
#pragma unroll
    for (int j = 0; j < 4; j++) acc[i][j] = (f32x4){0.f, 0.f, 0.f, 0.f};

  const int ar = t >> 2, ak = (t & 3) * 8;
  const float* xrow = x + (t0 + ar) * DD + ak;
  float* yrow = y + (t0 + ar) * DD + ak;

  const int drow = lane >> 2;                       // dma row-within-16 group
  const int sch = ((lane & 3) ^ (drow & 3)) * 8;    // pre-swizzled source chunk
  auto BDMA = [&](int buf, int s) {
#pragma unroll
    for (int j = 0; j < 4; j++) {
      const int rbase = w * 64 + j * 16;
      const long gb = ((long)s * 256 + rbase + drow) * 32 + sch;
      dma16(w1h + gb, &Bh[buf][rbase * 32]);
      dma16(w1l + gb, &Bl[buf][rbase * 32]);
    }
  };

  float4 va = *(const float4*)(xrow);
  float4 vb = *(const float4*)(xrow + 4);
  BDMA(0, 0);
  int buf = 0;
  for (int s = 0; s < 32; s++) {
    *(float4*)(yrow + s * 32) = va;          // write-through residual base y = x
    *(float4*)(yrow + s * 32 + 4) = vb;
    float v[8] = {va.x, va.y, va.z, va.w, vb.x, vb.y, vb.z, vb.w};
    ux4 H, L;
    cvt8(v, H, L);
    *(ux4*)(Ah + ar * PK + ak) = H;
    *(ux4*)(Al + ar * PK + ak) = L;
    if (s < 31) {
      va = *(const float4*)(xrow + (s + 1) * 32);      // prefetch x(s+1)
      vb = *(const float4*)(xrow + (s + 1) * 32 + 4);
      BDMA(buf ^ 1, s + 1);                            // next B-tile in flight
      __builtin_amdgcn_sched_barrier(0);
      asm volatile("s_waitcnt vmcnt(12) lgkmcnt(0)" ::: "memory");
    } else {
      __builtin_amdgcn_sched_barrier(0);
      asm volatile("s_waitcnt vmcnt(0) lgkmcnt(0)" ::: "memory");
    }
    __builtin_amdgcn_sched_barrier(0);
    __builtin_amdgcn_s_barrier();           // A visible + B(s) landed
    __builtin_amdgcn_sched_barrier(0);
    const u16* Bhc = Bh[buf];
    const u16* Blc = Bl[buf];
    short8 a_h[4], a_l[4];
#pragma unroll
    for (int mi = 0; mi < 4; mi++) {
      const int row = (mi * 16 + qi) * PK + g * 8;
      a_h[mi] = *(const short8*)(Ah + row);
      a_l[mi] = *(const short8*)(Al + row);
    }
#pragma unroll
    for (int ni = 0; ni < 4; ni++) {
      const int brow = (w * 64 + ni * 16 + qi) * 32 + ((g ^ (qi & 3)) * 8);
      short8 b_h = *(const short8*)(Bhc + brow);
      short8 b_l = *(const short8*)(Blc + brow);
#pragma unroll
      for (int mi = 0; mi < 4; mi++) {
        acc[mi][ni] = MFMA16(a_h[mi], b_h, acc[mi][ni]);
        acc[mi][ni] = MFMA16(a_h[mi], b_l, acc[mi][ni]);
        acc[mi][ni] = MFMA16(a_l[mi], b_h, acc[mi][ni]);
      }
    }
    __builtin_amdgcn_sched_barrier(0);
    __builtin_amdgcn_s_barrier();           // readers done; A/B(buf) reusable
    __builtin_amdgcn_sched_barrier(0);
    buf ^= 1;
  }
  // epilogue: relu + layer-2 (fp32), reduce over qi then across col-waves
  float part[4][4];
#pragma unroll
  for (int mi = 0; mi < 4; mi++)
#pragma unroll
    for (int r = 0; r < 4; r++) part[mi][r] = 0.f;
#pragma unroll
  for (int ni = 0; ni < 4; ni++) {
    const int col = w * 64 + ni * 16 + qi;
    const float b1v = b1[col], w2v = w2[col];
#pragma unroll
    for (int mi = 0; mi < 4; mi++)
#pragma unroll
      for (int r = 0; r < 4; r++) {
        float hv = acc[mi][ni][r] + b1v;
        hv = hv > 0.f ? hv : 0.f;
        part[mi][r] = fmaf(hv, w2v, part[mi][r]);
      }
  }
#pragma unroll
  for (int mi = 0; mi < 4; mi++)
#pragma unroll
    for (int r = 0; r < 4; r++) {
      float p = part[mi][r];
      p += __shfl_xor(p, 1, 16);
      p += __shfl_xor(p, 2, 16);
      p += __shfl_xor(p, 4, 16);
      p += __shfl_xor(p, 8, 16);
      part[mi][r] = p;
    }
  if (qi == 0) {
#pragma unroll
    for (int mi = 0; mi < 4; mi++)
#pragma unroll
      for (int r = 0; r < 4; r++)
        zp[mi * 16 + g * 4 + r][w] = part[mi][r];
  }
  __syncthreads();
  if (t < 64) z[t0 + t] = (zp[t][0] + zp[t][1]) + (zp[t][2] + zp[t][3]);
}

// ---------- per-batch top-k: exact 4-round radix select (order-free output) ----
__global__ __launch_bounds__(1024) void k_topk(const float* __restrict__ z,
                                               int* __restrict__ sel) {
  __shared__ unsigned keys[LL];
  __shared__ int hist[256];
  __shared__ int ssum[256];
  __shared__ int tie[LL];
  __shared__ unsigned s_prefix;
  __shared__ int s_rem, s_cgt, s_ceq;
  const int b = blockIdx.x, t = threadIdx.x;
#pragma unroll
  for (int s_ = 0; s_ < 4; s_++) {
    const int i = t + s_ * 1024;
    unsigned u = __float_as_uint(z[b * LL + i]);
    u = (u & 0x80000000u) ? ~u : (u | 0x80000000u);
    keys[i] = u;
  }
  if (t == 0) { s_prefix = 0u; s_rem = KSEL; }
  __syncthreads();
  for (int shift = 24; shift >= 0; shift -= 8) {
    if (t < 256) hist[t] = 0;
    __syncthreads();
    const unsigned pref = s_prefix;
#pragma unroll
    for (int s_ = 0; s_ < 4; s_++) {
      const unsigned k = keys[t + s_ * 1024];
      const bool ok = (shift == 24) || ((k >> (shift + 8)) == (pref >> (shift + 8)));
      if (ok) atomicAdd(&hist[(k >> shift) & 255], 1);
    }
    __syncthreads();
    if (t < 256) ssum[t] = hist[t];
    __syncthreads();
    for (int off = 1; off < 256; off <<= 1) {
      int v = 0;
      if (t < 256) v = ssum[t] + ((t + off < 256) ? ssum[t + off] : 0);
      __syncthreads();
      if (t < 256) ssum[t] = v;
      __syncthreads();
    }
    const int rem = s_rem;
    __syncthreads();
    if (t < 256) {
      const int above = (t < 255) ? ssum[t + 1] : 0;
      if (above < rem && above + hist[t] >= rem) {
        s_prefix = pref | ((unsigned)t << shift);
        s_rem = rem - above;
      }
    }
    __syncthreads();
  }
  if (t == 0) { s_cgt = 0; s_ceq = 0; }
  __syncthreads();
  const unsigned T = s_prefix;
#pragma unroll
  for (int s_ = 0; s_ < 4; s_++) {
    const int i = t + s_ * 1024;
    const unsigned k = keys[i];
    if (k > T) {
      const int p = atomicAdd(&s_cgt, 1);
      sel[b * KSEL + p] = i;
    } else if (k == T) {
      const int p = atomicAdd(&s_ceq, 1);
      tie[p] = i;
    }
  }
  __syncthreads();
  const int ngt = s_cgt, need = KSEL - ngt, ceq = s_ceq;
  for (int j = t; j < ceq; j += 1024) {
    const int idx = tie[j];
    int rank = 0;
    for (int q2 = 0; q2 < ceq; q2++) rank += (tie[q2] < idx);
    if (rank < need) sel[b * KSEL + ngt + rank] = idx;
  }
}

// ---------- gather + split-convert selected rows once ----------
__global__ __launch_bounds__(256) void k_xsel(const float* __restrict__ x,
                                              const int* __restrict__ sel,
                                              u16* __restrict__ xsh, u16* __restrict__ xsl) {
  const int t = threadIdx.x;
  const int r = blockIdx.x * 8 + (t >> 5);   // 409 blocks * 8 = 3272 exactly
  const int c = (t & 31) * 32;
  const int b = r / KSEL;
  const int tok = sel[r];
  const float* src = x + ((long)b * LL + tok) * DD + c;
  u16* dh = xsh + (long)r * DD + c;
  u16* dl = xsl + (long)r * DD + c;
#pragma unroll
  for (int q = 0; q < 4; q++) {
    float4 f0 = *(const float4*)(src + q * 8);
    float4 f1 = *(const float4*)(src + q * 8 + 4);
    float v[8] = {f0.x, f0.y, f0.z, f0.w, f1.x, f1.y, f1.z, f1.w};
    ux4 H, L;
    cvt8(v, H, L);
    *(ux4*)(dh + q * 8) = H;
    *(ux4*)(dl + q * 8) = L;
  }
}

// ---------- qkv: BM=256 BN=128, 512 thr, 8 waves (4x2) of 64x64; full-DMA ------
// halves wh L2/L3 re-read vs BM=128 (13 row-tiles instead of 26)
__global__ __launch_bounds__(512) void k_qkv(
    const u16* __restrict__ xsh, const u16* __restrict__ xsl,
    const u16* __restrict__ wh,
    u16* __restrict__ qh, u16* __restrict__ kh,
    u16* __restrict__ vTh, u16* __restrict__ vTl) {
  __shared__ u16 AH[256 * 32], AL[256 * 32], BH[128 * 32];   // 40 KB
  const int t = threadIdx.x;
  const int nt = blockIdx.x, r0 = blockIdx.y * 256;
  const int w = t >> 6, lane = t & 63;
  const int wy = w >> 1, wx = w & 1;           // 4 row-waves x 2 col-waves
  const int qi = lane & 15, g = lane >> 4;
  f32x4 acc[4][4];
#pragma unroll
  for (int i = 0; i < 4; i++)
#pragma unroll
    for (int j = 0; j < 4; j++) acc[i][j] = (f32x4){0.f, 0.f, 0.f, 0.f};

  const int drow = lane >> 2;
  const int sch = ((lane & 3) ^ (drow & 3)) * 8;   // pre-swizzled source chunk
  auto DMA = [&](int s) {
    // A: each wave stages rows w*32..w*32+31 (hi+lo)
#pragma unroll
    for (int j = 0; j < 2; j++) {
      const int rbase = w * 32 + j * 16;
      int rg = r0 + rbase + drow;
      rg = rg < MTOT ? rg : MTOT - 1;
      dma16(xsh + (long)rg * DD + s * 32 + sch, AH + rbase * 32);
      dma16(xsl + (long)rg * DD + s * 32 + sch, AL + rbase * 32);
    }
    // B: each wave stages rows w*16..w*16+15
    {
      const int rbase = w * 16;
      dma16(wh + ((long)s * NT3 + nt * 128 + rbase + drow) * 32 + sch, BH + rbase * 32);
    }
  };

  DMA(0);
  for (int s = 0; s < 32; s++) {
    __syncthreads();                          // dma drained, tile ready
    short8 a_h[4], a_l[4];
#pragma unroll
    for (int mi = 0; mi < 4; mi++) {
      const int row = (wy * 64 + mi * 16 + qi) * 32 + ((g ^ (qi & 3)) * 8);
      a_h[mi] = *(const short8*)(AH + row);
      a_l[mi] = *(const short8*)(AL + row);
    }
#pragma unroll
    for (int ni = 0; ni < 4; ni++) {
      const int brow = (wx * 64 + ni * 16 + qi) * 32 + ((g ^ (qi & 3)) * 8);
      short8 b_h = *(const short8*)(BH + brow);
#pragma unroll
      for (int mi = 0; mi < 4; mi++) {
        acc[mi][ni] = MFMA16(a_h[mi], b_h, acc[mi][ni]);
        acc[mi][ni] = MFMA16(a_l[mi], b_h, acc[mi][ni]);
      }
    }
    __syncthreads();                          // readers done
    if (s < 31) DMA(s + 1);
  }
  // epilogue: q/k bf16-hi row-major; v split-bf16 transposed [bh][d][key]
#pragma unroll
  for (int mi = 0; mi < 4; mi++) {
#pragma unroll
    for (int rr = 0; rr < 4; rr++) {
      const int r = r0 + wy * 64 + mi * 16 + g * 4 + rr;
      if (r < MTOT) {
        if (nt < 16) {
          u16* dh = (nt < 8) ? qh : kh;
          const long base = (long)r * DD + (nt & 7) * 128 + wx * 64 + qi;
#pragma unroll
          for (int ni = 0; ni < 4; ni++)
            dh[base + ni * 16] = bfh(acc[mi][ni][rr]);
        } else {
          const int b2 = r / KSEL;
          const int key = r - b2 * KSEL;
          const int hh = (nt - 16) * 2 + wx;
          const long vbase = ((long)(b2 * 16 + hh) * 64) * VP + key;
#pragma unroll
          for (int ni = 0; ni < 4; ni++) {
            const int d = ni * 16 + qi;
            const float f = acc[mi][ni][rr];
            const u16 hh_ = bfh(f);
            vTh[vbase + (long)d * VP] = hh_;
            vTl[vbase + (long)d * VP] = bfh(f - bff(hh_));
          }
        }
      }
    }
  }
}

// ---------- MFMA flash attention: QBLK=128, 1-term QK, 2-term PV --------------
__global__ __launch_bounds__(512) void k_attn(
    const u16* __restrict__ qh, const u16* __restrict__ kh,
    const u16* __restrict__ vh, const u16* __restrict__ vl,
    u16* __restrict__ aoh, u16* __restrict__ aol) {
  __shared__ u16 Kh[64][72], Vh[64][72], Vl[64][72], P[128][72];
  const int t = threadIdx.x;
  const int qt = blockIdx.x, h = blockIdx.y, b = blockIdx.z;
  const int w = t >> 6, lane = t & 63;
  const int g = lane >> 4, qi = lane & 15;
  const ux4 zz = (ux4){0u, 0u, 0u, 0u};
  const int q_ = qt * 128 + w * 16 + qi;
  const int qc = q_ < KSEL ? q_ : KSEL - 1;
  const long qbase = (long)(b * KSEL + qc) * DD + h * 64;
  short8 qf_h[2];
#pragma unroll
  for (int ks = 0; ks < 2; ks++)
    qf_h[ks] = *(const short8*)(qh + qbase + ks * 32 + g * 8);
  float m = -1e30f, l = 0.f;
  f32x4 o[4];
#pragma unroll
  for (int dt = 0; dt < 4; dt++) o[dt] = (f32x4){0.f, 0.f, 0.f, 0.f};

  const int sr = (t & 255) >> 2, sc = (t & 3) * 16;
  ux4 p0, p1, p2, p3;
  auto PREF = [&](int kt) {
    if (t < 256) {
      const int gk = kt * 64 + sr;
      if (gk < KSEL) {
        const long ga = (long)(b * KSEL + gk) * DD + h * 64 + sc;
        p0 = *(const ux4*)(kh + ga);
        p1 = *(const ux4*)(kh + ga + 8);
      } else {
        p0 = zz; p1 = zz;
      }
    } else {
      const long va_ = ((long)((b * 16 + h) * 64 + sr)) * VP + kt * 64 + sc;
      const int key0 = kt * 64 + sc;
      if (key0 + 15 < KSEL) {
        p0 = *(const ux4*)(vh + va_);
        p1 = *(const ux4*)(vh + va_ + 8);
        p2 = *(const ux4*)(vl + va_);
        p3 = *(const ux4*)(vl + va_ + 8);
      } else {
#pragma unroll
        for (int j = 0; j < 4; j++) {
          u16 a0 = (key0 + 2 * j < KSEL) ? vh[va_ + 2 * j] : (u16)0;
          u16 a1 = (key0 + 2 * j + 1 < KSEL) ? vh[va_ + 2 * j + 1] : (u16)0;
          u16 a2 = (key0 + 8 + 2 * j < KSEL) ? vh[va_ + 8 + 2 * j] : (u16)0;
          u16 a3 = (key0 + 9 + 2 * j < KSEL) ? vh[va_ + 9 + 2 * j] : (u16)0;
          p0[j] = (unsigned)a0 | ((unsigned)a1 << 16);
          p1[j] = (unsigned)a2 | ((unsigned)a3 << 16);
          u16 c0 = (key0 + 2 * j < KSEL) ? vl[va_ + 2 * j] : (u16)0;
          u16 c1 = (key0 + 2 * j + 1 < KSEL) ? vl[va_ + 2 * j + 1] : (u16)0;
          u16 c2 = (key0 + 8 + 2 * j < KSEL) ? vl[va_ + 8 + 2 * j] : (u16)0;
          u16 c3 = (key0 + 9 + 2 * j < KSEL) ? vl[va_ + 9 + 2 * j] : (u16)0;
          p2[j] = (unsigned)c0 | ((unsigned)c1 << 16);
          p3[j] = (unsigned)c2 | ((unsigned)c3 << 16);
        }
      }
    }
  };

  PREF(0);
  for (int kt = 0; kt < 7; kt++) {
    __syncthreads();
    if (t < 256) {
      *(ux4*)(&Kh[sr][sc]) = p0; *(ux4*)(&Kh[sr][sc + 8]) = p1;
    } else {
      *(ux4*)(&Vh[sr][sc]) = p0; *(ux4*)(&Vh[sr][sc + 8]) = p1;
      *(ux4*)(&Vl[sr][sc]) = p2; *(ux4*)(&Vl[sr][sc + 8]) = p3;
    }
    __syncthreads();
    if (kt < 6) PREF(kt + 1);
    f32x4 s[4];
#pragma unroll
    for (int mt = 0; mt < 4; mt++) s[mt] = (f32x4){0.f, 0.f, 0.f, 0.f};
#pragma unroll
    for (int ks = 0; ks < 2; ks++) {
#pragma unroll
      for (int mt = 0; mt < 4; mt++) {
        short8 a_h = *(const short8*)(&Kh[mt * 16 + qi][ks * 32 + g * 8]);
        s[mt] = MFMA16(a_h, qf_h[ks], s[mt]);
      }
    }
    float tmax = -1e30f;
#pragma unroll
    for (int mt = 0; mt < 4; mt++)
#pragma unroll
      for (int r = 0; r < 4; r++) {
        const int key = kt * 64 + mt * 16 + g * 4 + r;
        const float sv = s[mt][r] * 0.125f;
        s[mt][r] = sv;
        if (key < KSEL) tmax = fmaxf(tmax, sv);
      }
    tmax = fmaxf(tmax, __shfl_xor(tmax, 16));
    tmax = fmaxf(tmax, __shfl_xor(tmax, 32));
    const float mn = fmaxf(m, tmax);
    const float scale = __expf(m - mn);
    float part = 0.f;
#pragma unroll
    for (int mt = 0; mt < 4; mt++)
#pragma unroll
      for (int r = 0; r < 4; r++) {
        const int key = kt * 64 + mt * 16 + g * 4 + r;
        const float p = (key < KSEL) ? __expf(s[mt][r] - mn) : 0.f;
        part += p;
        P[w * 16 + qi][mt * 16 + g * 4 + r] = bfh(p);
      }
    part += __shfl_xor(part, 16);
    part += __shfl_xor(part, 32);
    l = l * scale + part;
    m = mn;
#pragma unroll
    for (int dt = 0; dt < 4; dt++)
#pragma unroll
      for (int r = 0; r < 4; r++) o[dt][r] *= scale;
#pragma unroll
    for (int ks = 0; ks < 2; ks++) {
      const short8 b_p = *(const short8*)(&P[w * 16 + qi][ks * 32 + g * 8]);
#pragma unroll
      for (int dt = 0; dt < 4; dt++) {
        short8 a_h = *(const short8*)(&Vh[dt * 16 + qi][ks * 32 + g * 8]);
        short8 a_l = *(const short8*)(&Vl[dt * 16 + qi][ks * 32 + g * 8]);
        o[dt] = MFMA16(a_h, b_p, o[dt]);
        o[dt] = MFMA16(a_l, b_p, o[dt]);
      }
    }
  }
  if (q_ < KSEL) {
    const float inv = 1.f / l;
    const long base_o = ((long)b * KSEL + q_) * DD + h * 64;
#pragma unroll
    for (int dt = 0; dt < 4; dt++) {
      us4 h4, l4;
#pragma unroll
      for (int rr = 0; rr < 4; rr++) {
        const float f = o[dt][rr] * inv;
        const u16 hh_ = bfh(f);
        h4[rr] = hh_;
        l4[rr] = bfh(f - bff(hh_));
      }
      *(us4*)(aoh + base_o + dt * 16 + g * 4) = h4;
      *(us4*)(aol + base_o + dt * 16 + g * 4) = l4;
    }
  }
}

// ---------- out-proj: full-DMA (chunk-swizzled), BM=128, 2-term ---------------
__global__ __launch_bounds__(256) void k_oproj(
    const u16* __restrict__ aoh, const u16* __restrict__ aol,
    const u16* __restrict__ wh,
    const int* __restrict__ sel, const float* __restrict__ x,
    const float* __restrict__ resw, float* __restrict__ y) {
  __shared__ u16 AH[128 * 32], AL[128 * 32], BH[128 * 32];
  const int t = threadIdx.x;
  const int nt = blockIdx.x, r0 = blockIdx.y * 128;
  const int w = t >> 6, lane = t & 63;
  const int wy = w >> 1, wx = w & 1;
  const int qi = lane & 15, g = lane >> 4;
  f32x4 acc[4][4];
#pragma unroll
  for (int i = 0; i < 4; i++)
#pragma unroll
    for (int j = 0; j < 4; j++) acc[i][j] = (f32x4){0.f, 0.f, 0.f, 0.f};

  const int drow = lane >> 2;
  const int sch = ((lane & 3) ^ (drow & 3)) * 8;
  auto DMA = [&](int s) {
#pragma unroll
    for (int j = 0; j < 2; j++) {
      const int rbase = w * 32 + j * 16;
      int rg = r0 + rbase + drow;
      rg = rg < MTOT ? rg : MTOT - 1;
      dma16(aoh + (long)rg * DD + s * 32 + sch, AH + rbase * 32);
      dma16(aol + (long)rg * DD + s * 32 + sch, AL + rbase * 32);
      dma16(wh + ((long)s * DD + nt * 128 + rbase + drow) * 32 + sch, BH + rbase * 32);
    }
  };

  DMA(0);
  for (int s = 0; s < 32; s++) {
    __syncthreads();
    short8 a_h[4], a_l[4];
#pragma unroll
    for (int mi = 0; mi < 4; mi++) {
      const int row = (wy * 64 + mi * 16 + qi) * 32 + ((g ^ (qi & 3)) * 8);
      a_h[mi] = *(const short8*)(AH + row);
      a_l[mi] = *(const short8*)(AL + row);
    }
#pragma unroll
    for (int ni = 0; ni < 4; ni++) {
      const int brow = (wx * 64 + ni * 16 + qi) * 32 + ((g ^ (qi & 3)) * 8);
      short8 b_h = *(const short8*)(BH + brow);
#pragma unroll
      for (int mi = 0; mi < 4; mi++) {
        acc[mi][ni] = MFMA16(a_h[mi], b_h, acc[mi][ni]);
        acc[mi][ni] = MFMA16(a_l[mi], b_h, acc[mi][ni]);
      }
    }
    __syncthreads();
    if (s < 31) DMA(s + 1);
  }
  const float rw = resw[0];
#pragma unroll
  for (int mi = 0; mi < 4; mi++)
#pragma unroll
    for (int rr = 0; rr < 4; rr++) {
      const int r = r0 + wy * 64 + mi * 16 + g * 4 + rr;
      if (r < MTOT) {
        const int bb = r / KSEL;
        const int tok = sel[r];
        const long off = ((long)bb * LL + tok) * DD + nt * 128 + wx * 64 + qi;
#pragma unroll
        for (int ni = 0; ni < 4; ni++)
          y[off + ni * 16] = fmaf(rw, acc[mi][ni][rr], x[off + ni * 16]);
      }
    }
}

extern "C" void kernel_launch(void* const* d_in, const int* in_sizes, int n_in,
                              void* d_out, int out_size, void* d_ws, size_t ws_size,
                              hipStream_t stream) {
  const float* x = (const float*)d_in[0];
  const float* w1 = (const float*)d_in[1];
  const float* b1 = (const float*)d_in[2];
  const float* w2 = (const float*)d_in[3];
  // d_in[4] = b2: constant shift through monotone sigmoid -> irrelevant to top-k
  const float* wqkv = (const float*)d_in[5];
  const float* wout = (const float*)d_in[6];
  const float* resw = (const float*)d_in[7];
  float* y = (float*)d_out;

  char* ws = (char*)d_ws;
  float* z = (float*)(ws);                  // 131072 B
  int* sel = (int*)(ws + 131072);           // 16384 B
  u16* w1h = (u16*)(ws + 147456);           // 524288 B
  u16* w1l = (u16*)(ws + 671744);           // 524288 B
  u16* wqh = (u16*)(ws + 1196032);          // 6291456 B
  u16* woh = (u16*)(ws + 13778944);         // 2097152 B
  u16* qh = (u16*)(ws + 17973248);          // 6701056 B
  u16* kh = (u16*)(ws + 31375360);          // 6701056 B
  u16* vTh = (u16*)(ws + 44777472);         // 7340032 B
  u16* vTl = (u16*)(ws + 52117504);         // 7340032 B
  u16* xsh = (u16*)(ws + 59457536);         // 6701056 B (aliased: ao hi after qkv)
  u16* xsl = (u16*)(ws + 66158592);         // 6701056 B (aliased: ao lo after qkv)
  u16* aoh = xsh;  // xs dead after k_qkv; stream-ordered reuse
  u16* aol = xsl;

  k_prep<<<dim3(1, 32), 256, 0, stream>>>(w1, 256, w1h, w1l);
  k_prep<<<dim3(12, 32), 256, 0, stream>>>(wqkv, NT3, wqh, nullptr);
  k_prep<<<dim3(4, 32), 256, 0, stream>>>(wout, DD, woh, nullptr);
  k_score<<<512, 256, 0, stream>>>(x, w1h, w1l, b1, w2, z, y);
  k_topk<<<BB, 1024, 0, stream>>>(z, sel);
  k_xsel<<<409, 256, 0, stream>>>(x, sel, xsh, xsl);
  k_qkv<<<dim3(24, 13), 512, 0, stream>>>(xsh, xsl, wqh, qh, kh, vTh, vTl);
  k_attn<<<dim3(4, HH, BB), 512, 0, stream>>>(qh, kh, vTh, vTl, aoh, aol);
  k_oproj<<<dim3(8, 26), 256, 0, stream>>>(aoh, aol, woh, sel, x, resw, y);
}

// Round 18
// 264.691 us; speedup vs baseline: 1.0862x; 1.0862x over previous
//
#include <hip/hip_runtime.h>
#include <cstdint>

#define BB 8
#define LL 4096
#define DD 1024
#define HH 16
#define KSEL 409
#define NT3 3072
#define MTOT (BB * KSEL)   // 3272 flat selected rows
#define PK 40              // padded LDS pitch (u16) for reg-staged A tiles
#define VP 448             // vT key-pitch

typedef unsigned short u16;
typedef unsigned int u32;
typedef __attribute__((ext_vector_type(4))) unsigned int ux4;
typedef __attribute__((ext_vector_type(4))) unsigned short us4;
typedef __attribute__((ext_vector_type(8))) short short8;
typedef __attribute__((ext_vector_type(4))) float f32x4;

typedef const u32 __attribute__((address_space(1)))* gas_p;
typedef u32 __attribute__((address_space(3)))* las_p;

__device__ __forceinline__ void dma16(const void* g, void* l) {
  __builtin_amdgcn_global_load_lds((gas_p)g, (las_p)l, 16, 0, 0);
}

__device__ __forceinline__ u16 bfh(float f) {
  unsigned u = __float_as_uint(f);
  return (u16)((u + 0x7fffu + ((u >> 16) & 1u)) >> 16);
}
__device__ __forceinline__ float bff(u16 h) { return __uint_as_float(((unsigned)h) << 16); }

__device__ __forceinline__ void cvt8(const float* v, ux4& H, ux4& L) {
#pragma unroll
  for (int i = 0; i < 4; i++) {
    u16 h0 = bfh(v[2 * i]), h1 = bfh(v[2 * i + 1]);
    u16 l0 = bfh(v[2 * i] - bff(h0));
    u16 l1 = bfh(v[2 * i + 1] - bff(h1));
    H[i] = (unsigned)h0 | ((unsigned)h1 << 16);
    L[i] = (unsigned)l0 | ((unsigned)l1 << 16);
  }
}

#define MFMA16(A, B, C) __builtin_amdgcn_mfma_f32_16x16x32_bf16(A, B, C, 0, 0, 0)

// ---------- prep: fp32 weight [K][N] -> split-bf16 K-packed [s][n][32] ----------
__global__ __launch_bounds__(256) void k_prep(const float* __restrict__ w, int N,
                                              u16* __restrict__ h, u16* __restrict__ l) {
  __shared__ float T[32][257];
  const int t = threadIdx.x;
  const int n0 = blockIdx.x * 256, s = blockIdx.y;
#pragma unroll 4
  for (int r = 0; r < 32; r++) T[r][t] = w[((long)(s * 32 + r)) * N + n0 + t];
  __syncthreads();
  const long base = ((long)s * N + n0 + t) * 32;
#pragma unroll
  for (int q = 0; q < 4; q++) {
    float v[8];
#pragma unroll
    for (int i = 0; i < 8; i++) v[i] = T[q * 8 + i][t];
    ux4 H, L;
    cvt8(v, H, L);
    *(ux4*)(h + base + q * 8) = H;
    if (l) *(ux4*)(l + base + q * 8) = L;
  }
}

// ---------- scorer: counted-vmcnt pipeline; B dbuf DMA (chunk-swizzled), A reg --
// raw s_barrier + vmcnt(12): 12 = 2 y-stores + 2 x-prefetch + 8 next-tile DMAs
__global__ __launch_bounds__(256) void k_score(
    const float* __restrict__ x, const u16* __restrict__ w1h, const u16* __restrict__ w1l,
    const float* __restrict__ b1, const float* __restrict__ w2,
    float* __restrict__ z, float* __restrict__ y) {
  __shared__ u16 Ah[64 * PK], Al[64 * PK];        // 10.2 KB (single buf)
  __shared__ u16 Bh[2][256 * 32], Bl[2][256 * 32];// 64 KB (double buf, DMA)
  __shared__ float zp[64][4];
  const int t = threadIdx.x;
  const long t0 = (long)blockIdx.x * 64;
  const int w = t >> 6, lane = t & 63;
  const int g = lane >> 4, qi = lane & 15;
  f32x4 acc[4][4];
#pragma unroll
  for (int i = 0; i < 4; i++)
#pragma unroll
    for (int j = 0; j < 4; j++) acc[i][j] = (f32x4){0.f, 0.f, 0.f, 0.f};

  const int ar = t >> 2, ak = (t & 3) * 8;
  const float* xrow = x + (t0 + ar) * DD + ak;
  float* yrow = y + (t0 + ar) * DD + ak;

  const int drow = lane >> 2;                       // dma row-within-16 group
  const int sch = ((lane & 3) ^ (drow & 3)) * 8;    // pre-swizzled source chunk
  auto BDMA = [&](int buf, int s) {
#pragma unroll
    for (int j = 0; j < 4; j++) {
      const int rbase = w * 64 + j * 16;
      const long gb = ((long)s * 256 + rbase + drow) * 32 + sch;
      dma16(w1h + gb, &Bh[buf][rbase * 32]);
      dma16(w1l + gb, &Bl[buf][rbase * 32]);
    }
  };

  float4 va = *(const float4*)(xrow);
  float4 vb = *(const float4*)(xrow + 4);
  BDMA(0, 0);
  int buf = 0;
  for (int s = 0; s < 32; s++) {
    *(float4*)(yrow + s * 32) = va;          // write-through residual base y = x
    *(float4*)(yrow + s * 32 + 4) = vb;
    float v[8] = {va.x, va.y, va.z, va.w, vb.x, vb.y, vb.z, vb.w};
    ux4 H, L;
    cvt8(v, H, L);
    *(ux4*)(Ah + ar * PK + ak) = H;
    *(ux4*)(Al + ar * PK + ak) = L;
    if (s < 31) {
      va = *(const float4*)(xrow + (s + 1) * 32);      // prefetch x(s+1)
      vb = *(const float4*)(xrow + (s + 1) * 32 + 4);
      BDMA(buf ^ 1, s + 1);                            // next B-tile in flight
      __builtin_amdgcn_sched_barrier(0);
      asm volatile("s_waitcnt vmcnt(12) lgkmcnt(0)" ::: "memory");
    } else {
      __builtin_amdgcn_sched_barrier(0);
      asm volatile("s_waitcnt vmcnt(0) lgkmcnt(0)" ::: "memory");
    }
    __builtin_amdgcn_sched_barrier(0);
    __builtin_amdgcn_s_barrier();           // A visible + B(s) landed
    __builtin_amdgcn_sched_barrier(0);
    const u16* Bhc = Bh[buf];
    const u16* Blc = Bl[buf];
    short8 a_h[4], a_l[4];
#pragma unroll
    for (int mi = 0; mi < 4; mi++) {
      const int row = (mi * 16 + qi) * PK + g * 8;
      a_h[mi] = *(const short8*)(Ah + row);
      a_l[mi] = *(const short8*)(Al + row);
    }
#pragma unroll
    for (int ni = 0; ni < 4; ni++) {
      const int brow = (w * 64 + ni * 16 + qi) * 32 + ((g ^ (qi & 3)) * 8);
      short8 b_h = *(const short8*)(Bhc + brow);
      short8 b_l = *(const short8*)(Blc + brow);
#pragma unroll
      for (int mi = 0; mi < 4; mi++) {
        acc[mi][ni] = MFMA16(a_h[mi], b_h, acc[mi][ni]);
        acc[mi][ni] = MFMA16(a_h[mi], b_l, acc[mi][ni]);
        acc[mi][ni] = MFMA16(a_l[mi], b_h, acc[mi][ni]);
      }
    }
    __builtin_amdgcn_sched_barrier(0);
    __builtin_amdgcn_s_barrier();           // readers done; A/B(buf) reusable
    __builtin_amdgcn_sched_barrier(0);
    buf ^= 1;
  }
  // epilogue: relu + layer-2 (fp32), reduce over qi then across col-waves
  float part[4][4];
#pragma unroll
  for (int mi = 0; mi < 4; mi++)
#pragma unroll
    for (int r = 0; r < 4; r++) part[mi][r] = 0.f;
#pragma unroll
  for (int ni = 0; ni < 4; ni++) {
    const int col = w * 64 + ni * 16 + qi;
    const float b1v = b1[col], w2v = w2[col];
#pragma unroll
    for (int mi = 0; mi < 4; mi++)
#pragma unroll
      for (int r = 0; r < 4; r++) {
        float hv = acc[mi][ni][r] + b1v;
        hv = hv > 0.f ? hv : 0.f;
        part[mi][r] = fmaf(hv, w2v, part[mi][r]);
      }
  }
#pragma unroll
  for (int mi = 0; mi < 4; mi++)
#pragma unroll
    for (int r = 0; r < 4; r++) {
      float p = part[mi][r];
      p += __shfl_xor(p, 1, 16);
      p += __shfl_xor(p, 2, 16);
      p += __shfl_xor(p, 4, 16);
      p += __shfl_xor(p, 8, 16);
      part[mi][r] = p;
    }
  if (qi == 0) {
#pragma unroll
    for (int mi = 0; mi < 4; mi++)
#pragma unroll
      for (int r = 0; r < 4; r++)
        zp[mi * 16 + g * 4 + r][w] = part[mi][r];
  }
  __syncthreads();
  if (t < 64) z[t0 + t] = (zp[t][0] + zp[t][1]) + (zp[t][2] + zp[t][3]);
}

// ---------- per-batch top-k: exact 4-round radix select (order-free output) ----
__global__ __launch_bounds__(1024) void k_topk(const float* __restrict__ z,
                                               int* __restrict__ sel) {
  __shared__ unsigned keys[LL];
  __shared__ int hist[256];
  __shared__ int ssum[256];
  __shared__ int tie[LL];
  __shared__ unsigned s_prefix;
  __shared__ int s_rem, s_cgt, s_ceq;
  const int b = blockIdx.x, t = threadIdx.x;
#pragma unroll
  for (int s_ = 0; s_ < 4; s_++) {
    const int i = t + s_ * 1024;
    unsigned u = __float_as_uint(z[b * LL + i]);
    u = (u & 0x80000000u) ? ~u : (u | 0x80000000u);
    keys[i] = u;
  }
  if (t == 0) { s_prefix = 0u; s_rem = KSEL; }
  __syncthreads();
  for (int shift = 24; shift >= 0; shift -= 8) {
    if (t < 256) hist[t] = 0;
    __syncthreads();
    const unsigned pref = s_prefix;
#pragma unroll
    for (int s_ = 0; s_ < 4; s_++) {
      const unsigned k = keys[t + s_ * 1024];
      const bool ok = (shift == 24) || ((k >> (shift + 8)) == (pref >> (shift + 8)));
      if (ok) atomicAdd(&hist[(k >> shift) & 255], 1);
    }
    __syncthreads();
    if (t < 256) ssum[t] = hist[t];
    __syncthreads();
    for (int off = 1; off < 256; off <<= 1) {
      int v = 0;
      if (t < 256) v = ssum[t] + ((t + off < 256) ? ssum[t + off] : 0);
      __syncthreads();
      if (t < 256) ssum[t] = v;
      __syncthreads();
    }
    const int rem = s_rem;
    __syncthreads();
    if (t < 256) {
      const int above = (t < 255) ? ssum[t + 1] : 0;
      if (above < rem && above + hist[t] >= rem) {
        s_prefix = pref | ((unsigned)t << shift);
        s_rem = rem - above;
      }
    }
    __syncthreads();
  }
  if (t == 0) { s_cgt = 0; s_ceq = 0; }
  __syncthreads();
  const unsigned T = s_prefix;
#pragma unroll
  for (int s_ = 0; s_ < 4; s_++) {
    const int i = t + s_ * 1024;
    const unsigned k = keys[i];
    if (k > T) {
      const int p = atomicAdd(&s_cgt, 1);
      sel[b * KSEL + p] = i;
    } else if (k == T) {
      const int p = atomicAdd(&s_ceq, 1);
      tie[p] = i;
    }
  }
  __syncthreads();
  const int ngt = s_cgt, need = KSEL - ngt, ceq = s_ceq;
  for (int j = t; j < ceq; j += 1024) {
    const int idx = tie[j];
    int rank = 0;
    for (int q2 = 0; q2 < ceq; q2++) rank += (tie[q2] < idx);
    if (rank < need) sel[b * KSEL + ngt + rank] = idx;
  }
}

// ---------- gather + split-convert selected rows once ----------
__global__ __launch_bounds__(256) void k_xsel(const float* __restrict__ x,
                                              const int* __restrict__ sel,
                                              u16* __restrict__ xsh, u16* __restrict__ xsl) {
  const int t = threadIdx.x;
  const int r = blockIdx.x * 8 + (t >> 5);   // 409 blocks * 8 = 3272 exactly
  const int c = (t & 31) * 32;
  const int b = r / KSEL;
  const int tok = sel[r];
  const float* src = x + ((long)b * LL + tok) * DD + c;
  u16* dh = xsh + (long)r * DD + c;
  u16* dl = xsl + (long)r * DD + c;
#pragma unroll
  for (int q = 0; q < 4; q++) {
    float4 f0 = *(const float4*)(src + q * 8);
    float4 f1 = *(const float4*)(src + q * 8 + 4);
    float v[8] = {f0.x, f0.y, f0.z, f0.w, f1.x, f1.y, f1.z, f1.w};
    ux4 H, L;
    cvt8(v, H, L);
    *(ux4*)(dh + q * 8) = H;
    *(ux4*)(dl + q * 8) = L;
  }
}

// ---------- qkv: BM=128 BN=128, full-DMA (chunk-swizzled), 2-term --------------
__global__ __launch_bounds__(256) void k_qkv(
    const u16* __restrict__ xsh, const u16* __restrict__ xsl,
    const u16* __restrict__ wh,
    u16* __restrict__ qh, u16* __restrict__ kh,
    u16* __restrict__ vTh, u16* __restrict__ vTl) {
  __shared__ u16 AH[128 * 32], AL[128 * 32], BH[128 * 32];   // 24 KB
  const int t = threadIdx.x;
  const int nt = blockIdx.x, r0 = blockIdx.y * 128;
  const int w = t >> 6, lane = t & 63;
  const int wy = w >> 1, wx = w & 1;
  const int qi = lane & 15, g = lane >> 4;
  f32x4 acc[4][4];
#pragma unroll
  for (int i = 0; i < 4; i++)
#pragma unroll
    for (int j = 0; j < 4; j++) acc[i][j] = (f32x4){0.f, 0.f, 0.f, 0.f};

  const int drow = lane >> 2;
  const int sch = ((lane & 3) ^ (drow & 3)) * 8;   // pre-swizzled source chunk
  auto DMA = [&](int s) {
#pragma unroll
    for (int j = 0; j < 2; j++) {
      const int rbase = w * 32 + j * 16;
      int rg = r0 + rbase + drow;
      rg = rg < MTOT ? rg : MTOT - 1;
      dma16(xsh + (long)rg * DD + s * 32 + sch, AH + rbase * 32);
      dma16(xsl + (long)rg * DD + s * 32 + sch, AL + rbase * 32);
      dma16(wh + ((long)s * NT3 + nt * 128 + rbase + drow) * 32 + sch, BH + rbase * 32);
    }
  };

  DMA(0);
  for (int s = 0; s < 32; s++) {
    __syncthreads();                          // dma drained, tile ready
    short8 a_h[4], a_l[4];
#pragma unroll
    for (int mi = 0; mi < 4; mi++) {
      const int row = (wy * 64 + mi * 16 + qi) * 32 + ((g ^ (qi & 3)) * 8);
      a_h[mi] = *(const short8*)(AH + row);
      a_l[mi] = *(const short8*)(AL + row);
    }
#pragma unroll
    for (int ni = 0; ni < 4; ni++) {
      const int brow = (wx * 64 + ni * 16 + qi) * 32 + ((g ^ (qi & 3)) * 8);
      short8 b_h = *(const short8*)(BH + brow);
#pragma unroll
      for (int mi = 0; mi < 4; mi++) {
        acc[mi][ni] = MFMA16(a_h[mi], b_h, acc[mi][ni]);
        acc[mi][ni] = MFMA16(a_l[mi], b_h, acc[mi][ni]);
      }
    }
    __syncthreads();                          // readers done
    if (s < 31) DMA(s + 1);
  }
  // epilogue: q/k bf16-hi row-major; v split-bf16 transposed [bh][d][key]
#pragma unroll
  for (int mi = 0; mi < 4; mi++) {
#pragma unroll
    for (int rr = 0; rr < 4; rr++) {
      const int r = r0 + wy * 64 + mi * 16 + g * 4 + rr;
      if (r < MTOT) {
        if (nt < 16) {
          u16* dh = (nt < 8) ? qh : kh;
          const long base = (long)r * DD + (nt & 7) * 128 + wx * 64 + qi;
#pragma unroll
          for (int ni = 0; ni < 4; ni++)
            dh[base + ni * 16] = bfh(acc[mi][ni][rr]);
        } else {
          const int b2 = r / KSEL;
          const int key = r - b2 * KSEL;
          const int hh = (nt - 16) * 2 + wx;
          const long vbase = ((long)(b2 * 16 + hh) * 64) * VP + key;
#pragma unroll
          for (int ni = 0; ni < 4; ni++) {
            const int d = ni * 16 + qi;
            const float f = acc[mi][ni][rr];
            const u16 hh_ = bfh(f);
            vTh[vbase + (long)d * VP] = hh_;
            vTl[vbase + (long)d * VP] = bfh(f - bff(hh_));
          }
        }
      }
    }
  }
}

// ---------- MFMA flash attention: QBLK=128, 1-term QK, 2-term PV --------------
__global__ __launch_bounds__(512) void k_attn(
    const u16* __restrict__ qh, const u16* __restrict__ kh,
    const u16* __restrict__ vh, const u16* __restrict__ vl,
    u16* __restrict__ aoh, u16* __restrict__ aol) {
  __shared__ u16 Kh[64][72], Vh[64][72], Vl[64][72], P[128][72];
  const int t = threadIdx.x;
  const int qt = blockIdx.x, h = blockIdx.y, b = blockIdx.z;
  const int w = t >> 6, lane = t & 63;
  const int g = lane >> 4, qi = lane & 15;
  const ux4 zz = (ux4){0u, 0u, 0u, 0u};
  const int q_ = qt * 128 + w * 16 + qi;
  const int qc = q_ < KSEL ? q_ : KSEL - 1;
  const long qbase = (long)(b * KSEL + qc) * DD + h * 64;
  short8 qf_h[2];
#pragma unroll
  for (int ks = 0; ks < 2; ks++)
    qf_h[ks] = *(const short8*)(qh + qbase + ks * 32 + g * 8);
  float m = -1e30f, l = 0.f;
  f32x4 o[4];
#pragma unroll
  for (int dt = 0; dt < 4; dt++) o[dt] = (f32x4){0.f, 0.f, 0.f, 0.f};

  const int sr = (t & 255) >> 2, sc = (t & 3) * 16;
  ux4 p0, p1, p2, p3;
  auto PREF = [&](int kt) {
    if (t < 256) {
      const int gk = kt * 64 + sr;
      if (gk < KSEL) {
        const long ga = (long)(b * KSEL + gk) * DD + h * 64 + sc;
        p0 = *(const ux4*)(kh + ga);
        p1 = *(const ux4*)(kh + ga + 8);
      } else {
        p0 = zz; p1 = zz;
      }
    } else {
      const long va_ = ((long)((b * 16 + h) * 64 + sr)) * VP + kt * 64 + sc;
      const int key0 = kt * 64 + sc;
      if (key0 + 15 < KSEL) {
        p0 = *(const ux4*)(vh + va_);
        p1 = *(const ux4*)(vh + va_ + 8);
        p2 = *(const ux4*)(vl + va_);
        p3 = *(const ux4*)(vl + va_ + 8);
      } else {
#pragma unroll
        for (int j = 0; j < 4; j++) {
          u16 a0 = (key0 + 2 * j < KSEL) ? vh[va_ + 2 * j] : (u16)0;
          u16 a1 = (key0 + 2 * j + 1 < KSEL) ? vh[va_ + 2 * j + 1] : (u16)0;
          u16 a2 = (key0 + 8 + 2 * j < KSEL) ? vh[va_ + 8 + 2 * j] : (u16)0;
          u16 a3 = (key0 + 9 + 2 * j < KSEL) ? vh[va_ + 9 + 2 * j] : (u16)0;
          p0[j] = (unsigned)a0 | ((unsigned)a1 << 16);
          p1[j] = (unsigned)a2 | ((unsigned)a3 << 16);
          u16 c0 = (key0 + 2 * j < KSEL) ? vl[va_ + 2 * j] : (u16)0;
          u16 c1 = (key0 + 2 * j + 1 < KSEL) ? vl[va_ + 2 * j + 1] : (u16)0;
          u16 c2 = (key0 + 8 + 2 * j < KSEL) ? vl[va_ + 8 + 2 * j] : (u16)0;
          u16 c3 = (key0 + 9 + 2 * j < KSEL) ? vl[va_ + 9 + 2 * j] : (u16)0;
          p2[j] = (unsigned)c0 | ((unsigned)c1 << 16);
          p3[j] = (unsigned)c2 | ((unsigned)c3 << 16);
        }
      }
    }
  };

  PREF(0);
  for (int kt = 0; kt < 7; kt++) {
    __syncthreads();
    if (t < 256) {
      *(ux4*)(&Kh[sr][sc]) = p0; *(ux4*)(&Kh[sr][sc + 8]) = p1;
    } else {
      *(ux4*)(&Vh[sr][sc]) = p0; *(ux4*)(&Vh[sr][sc + 8]) = p1;
      *(ux4*)(&Vl[sr][sc]) = p2; *(ux4*)(&Vl[sr][sc + 8]) = p3;
    }
    __syncthreads();
    if (kt < 6) PREF(kt + 1);
    f32x4 s[4];
#pragma unroll
    for (int mt = 0; mt < 4; mt++) s[mt] = (f32x4){0.f, 0.f, 0.f, 0.f};
#pragma unroll
    for (int ks = 0; ks < 2; ks++) {
#pragma unroll
      for (int mt = 0; mt < 4; mt++) {
        short8 a_h = *(const short8*)(&Kh[mt * 16 + qi][ks * 32 + g * 8]);
        s[mt] = MFMA16(a_h, qf_h[ks], s[mt]);
      }
    }
    float tmax = -1e30f;
#pragma unroll
    for (int mt = 0; mt < 4; mt++)
#pragma unroll
      for (int r = 0; r < 4; r++) {
        const int key = kt * 64 + mt * 16 + g * 4 + r;
        const float sv = s[mt][r] * 0.125f;
        s[mt][r] = sv;
        if (key < KSEL) tmax = fmaxf(tmax, sv);
      }
    tmax = fmaxf(tmax, __shfl_xor(tmax, 16));
    tmax = fmaxf(tmax, __shfl_xor(tmax, 32));
    const float mn = fmaxf(m, tmax);
    const float scale = __expf(m - mn);
    float part = 0.f;
#pragma unroll
    for (int mt = 0; mt < 4; mt++)
#pragma unroll
      for (int r = 0; r < 4; r++) {
        const int key = kt * 64 + mt * 16 + g * 4 + r;
        const float p = (key < KSEL) ? __expf(s[mt][r] - mn) : 0.f;
        part += p;
        P[w * 16 + qi][mt * 16 + g * 4 + r] = bfh(p);
      }
    part += __shfl_xor(part, 16);
    part += __shfl_xor(part, 32);
    l = l * scale + part;
    m = mn;
#pragma unroll
    for (int dt = 0; dt < 4; dt++)
#pragma unroll
      for (int r = 0; r < 4; r++) o[dt][r] *= scale;
#pragma unroll
    for (int ks = 0; ks < 2; ks++) {
      const short8 b_p = *(const short8*)(&P[w * 16 + qi][ks * 32 + g * 8]);
#pragma unroll
      for (int dt = 0; dt < 4; dt++) {
        short8 a_h = *(const short8*)(&Vh[dt * 16 + qi][ks * 32 + g * 8]);
        short8 a_l = *(const short8*)(&Vl[dt * 16 + qi][ks * 32 + g * 8]);
        o[dt] = MFMA16(a_h, b_p, o[dt]);
        o[dt] = MFMA16(a_l, b_p, o[dt]);
      }
    }
  }
  if (q_ < KSEL) {
    const float inv = 1.f / l;
    const long base_o = ((long)b * KSEL + q_) * DD + h * 64;
#pragma unroll
    for (int dt = 0; dt < 4; dt++) {
      us4 h4, l4;
#pragma unroll
      for (int rr = 0; rr < 4; rr++) {
        const float f = o[dt][rr] * inv;
        const u16 hh_ = bfh(f);
        h4[rr] = hh_;
        l4[rr] = bfh(f - bff(hh_));
      }
      *(us4*)(aoh + base_o + dt * 16 + g * 4) = h4;
      *(us4*)(aol + base_o + dt * 16 + g * 4) = l4;
    }
  }
}

// ---------- out-proj: full-DMA (chunk-swizzled), BM=128, 2-term ---------------
__global__ __launch_bounds__(256) void k_oproj(
    const u16* __restrict__ aoh, const u16* __restrict__ aol,
    const u16* __restrict__ wh,
    const int* __restrict__ sel, const float* __restrict__ x,
    const float* __restrict__ resw, float* __restrict__ y) {
  __shared__ u16 AH[128 * 32], AL[128 * 32], BH[128 * 32];
  const int t = threadIdx.x;
  const int nt = blockIdx.x, r0 = blockIdx.y * 128;
  const int w = t >> 6, lane = t & 63;
  const int wy = w >> 1, wx = w & 1;
  const int qi = lane & 15, g = lane >> 4;
  f32x4 acc[4][4];
#pragma unroll
  for (int i = 0; i < 4; i++)
#pragma unroll
    for (int j = 0; j < 4; j++) acc[i][j] = (f32x4){0.f, 0.f, 0.f, 0.f};

  const int drow = lane >> 2;
  const int sch = ((lane & 3) ^ (drow & 3)) * 8;
  auto DMA = [&](int s) {
#pragma unroll
    for (int j = 0; j < 2; j++) {
      const int rbase = w * 32 + j * 16;
      int rg = r0 + rbase + drow;
      rg = rg < MTOT ? rg : MTOT - 1;
      dma16(aoh + (long)rg * DD + s * 32 + sch, AH + rbase * 32);
      dma16(aol + (long)rg * DD + s * 32 + sch, AL + rbase * 32);
      dma16(wh + ((long)s * DD + nt * 128 + rbase + drow) * 32 + sch, BH + rbase * 32);
    }
  };

  DMA(0);
  for (int s = 0; s < 32; s++) {
    __syncthreads();
    short8 a_h[4], a_l[4];
#pragma unroll
    for (int mi = 0; mi < 4; mi++) {
      const int row = (wy * 64 + mi * 16 + qi) * 32 + ((g ^ (qi & 3)) * 8);
      a_h[mi] = *(const short8*)(AH + row);
      a_l[mi] = *(const short8*)(AL + row);
    }
#pragma unroll
    for (int ni = 0; ni < 4; ni++) {
      const int brow = (wx * 64 + ni * 16 + qi) * 32 + ((g ^ (qi & 3)) * 8);
      short8 b_h = *(const short8*)(BH + brow);
#pragma unroll
      for (int mi = 0; mi < 4; mi++) {
        acc[mi][ni] = MFMA16(a_h[mi], b_h, acc[mi][ni]);
        acc[mi][ni] = MFMA16(a_l[mi], b_h, acc[mi][ni]);
      }
    }
    __syncthreads();
    if (s < 31) DMA(s + 1);
  }
  const float rw = resw[0];
#pragma unroll
  for (int mi = 0; mi < 4; mi++)
#pragma unroll
    for (int rr = 0; rr < 4; rr++) {
      const int r = r0 + wy * 64 + mi * 16 + g * 4 + rr;
      if (r < MTOT) {
        const int bb = r / KSEL;
        const int tok = sel[r];
        const long off = ((long)bb * LL + tok) * DD + nt * 128 + wx * 64 + qi;
#pragma unroll
        for (int ni = 0; ni < 4; ni++)
          y[off + ni * 16] = fmaf(rw, acc[mi][ni][rr], x[off + ni * 16]);
      }
    }
}

extern "C" void kernel_launch(void* const* d_in, const int* in_sizes, int n_in,
                              void* d_out, int out_size, void* d_ws, size_t ws_size,
                              hipStream_t stream) {
  const float* x = (const float*)d_in[0];
  const float* w1 = (const float*)d_in[1];
  const float* b1 = (const float*)d_in[2];
  const float* w2 = (const float*)d_in[3];
  // d_in[4] = b2: constant shift through monotone sigmoid -> irrelevant to top-k
  const float* wqkv = (const float*)d_in[5];
  const float* wout = (const float*)d_in[6];
  const float* resw = (const float*)d_in[7];
  float* y = (float*)d_out;

  char* ws = (char*)d_ws;
  float* z = (float*)(ws);                  // 131072 B
  int* sel = (int*)(ws + 131072);           // 16384 B
  u16* w1h = (u16*)(ws + 147456);           // 524288 B
  u16* w1l = (u16*)(ws + 671744);           // 524288 B
  u16* wqh = (u16*)(ws + 1196032);          // 6291456 B
  u16* woh = (u16*)(ws + 13778944);         // 2097152 B
  u16* qh = (u16*)(ws + 17973248);          // 6701056 B
  u16* kh = (u16*)(ws + 31375360);          // 6701056 B
  u16* vTh = (u16*)(ws + 44777472);         // 7340032 B
  u16* vTl = (u16*)(ws + 52117504);         // 7340032 B
  u16* xsh = (u16*)(ws + 59457536);         // 6701056 B (aliased: ao hi after qkv)
  u16* xsl = (u16*)(ws + 66158592);         // 6701056 B (aliased: ao lo after qkv)
  u16* aoh = xsh;  // xs dead after k_qkv; stream-ordered reuse
  u16* aol = xsl;

  k_prep<<<dim3(1, 32), 256, 0, stream>>>(w1, 256, w1h, w1l);
  k_prep<<<dim3(12, 32), 256, 0, stream>>>(wqkv, NT3, wqh, nullptr);
  k_prep<<<dim3(4, 32), 256, 0, stream>>>(wout, DD, woh, nullptr);
  k_score<<<512, 256, 0, stream>>>(x, w1h, w1l, b1, w2, z, y);
  k_topk<<<BB, 1024, 0, stream>>>(z, sel);
  k_xsel<<<409, 256, 0, stream>>>(x, sel, xsh, xsl);
  k_qkv<<<dim3(24, 26), 256, 0, stream>>>(xsh, xsl, wqh, qh, kh, vTh, vTl);
  k_attn<<<dim3(4, HH, BB), 512, 0, stream>>>(qh, kh, vTh, vTl, aoh, aol);
  k_oproj<<<dim3(8, 26), 256, 0, stream>>>(aoh, aol, woh, sel, x, resw, y);
}